// Round 1
// baseline (11893.511 us; speedup 1.0000x reference)
//
#include <hip/hip_runtime.h>
#include <stdint.h>

// ---------------------------------------------------------------------------
// KerasLMU fused recurrence:
//   state s = [h(512) ; m(256)],  BigW = [[W_h | W_m@A],[0 | A]]  (768x768)
//   s_t = act( pre_t + BigW @ s_{t-1} ),  act = leakyrelu on h-rows, identity on m-rows
//   pre_t = [ xW_x + (W_m b) u_t ; b u_t ]
// Sequential kernel: 4 groups x 16 batches, 12 WGs/group (8 h-WGs, 4 m-WGs),
// fp16 3-term-split MFMA (16x16x32), weights in VGPRs, state exchange via
// agent-scope atomics + per-WG arrival counters.
// ---------------------------------------------------------------------------

typedef _Float16 half8 __attribute__((ext_vector_type(8)));
typedef float f32x4 __attribute__((ext_vector_type(4)));

union H8 {
    half8 h;
    unsigned int u[4];
};

__device__ __forceinline__ half8 load_w_frag(const _Float16* W, size_t base) {
    // elems 0..3 = k..k+3, elems 4..7 = k+16..k+19
    H8 r;
    const unsigned int* p0 = (const unsigned int*)(W + base);
    const unsigned int* p1 = (const unsigned int*)(W + base + 16);
    r.u[0] = p0[0]; r.u[1] = p0[1];
    r.u[2] = p1[0]; r.u[3] = p1[1];
    return r.h;
}

__device__ __forceinline__ void unpack_state(unsigned long long q0, unsigned long long q1,
                                             unsigned long long q2, unsigned long long q3,
                                             half8& hi, half8& lo) {
    unsigned int a0 = (unsigned int)q0, a1 = (unsigned int)(q0 >> 32);
    unsigned int b0 = (unsigned int)q1, b1 = (unsigned int)(q1 >> 32);
    unsigned int c0 = (unsigned int)q2, c1 = (unsigned int)(q2 >> 32);
    unsigned int d0 = (unsigned int)q3, d1 = (unsigned int)(q3 >> 32);
    H8 h, l;
    h.u[0] = (a0 & 0xffffu) | (a1 << 16);  l.u[0] = (a0 >> 16) | (a1 & 0xffff0000u);
    h.u[1] = (b0 & 0xffffu) | (b1 << 16);  l.u[1] = (b0 >> 16) | (b1 & 0xffff0000u);
    h.u[2] = (c0 & 0xffffu) | (c1 << 16);  l.u[2] = (c0 >> 16) | (c1 & 0xffff0000u);
    h.u[3] = (d0 & 0xffffu) | (d1 << 16);  l.u[3] = (d0 >> 16) | (d1 & 0xffff0000u);
    hi = h.h; lo = l.h;
}

#define MFMA16(a, b, c) __builtin_amdgcn_mfma_f32_16x16x32_f16((a), (b), (c), 0, 0, 0)

// ---------------------------------------------------------------------------
// k_prep: build BigW fp16 splits (768x768), WxT splits (512x128), wmb (512)
// ---------------------------------------------------------------------------
__global__ void k_prep(const float* __restrict__ A, const float* __restrict__ Bv,
                       const float* __restrict__ W_x, const float* __restrict__ W_h,
                       const float* __restrict__ W_m,
                       _Float16* __restrict__ Whi, _Float16* __restrict__ Wlo,
                       _Float16* __restrict__ WxThi, _Float16* __restrict__ WxTlo,
                       float* __restrict__ wmb) {
    int bid = blockIdx.x, tid = threadIdx.x;
    if (bid < 768) {
        int r = bid;
        for (int c = tid; c < 768; c += 256) {
            float v;
            if (r < 512) {
                if (c < 512) {
                    v = W_h[(size_t)r * 512 + c];
                } else {
                    float s = 0.f;
                    const float* wm = W_m + (size_t)r * 256;
                    int j = c - 512;
                    for (int i = 0; i < 256; ++i) s += wm[i] * A[(size_t)i * 256 + j];
                    v = s;
                }
            } else {
                v = (c < 512) ? 0.f : A[(size_t)(r - 512) * 256 + (c - 512)];
            }
            _Float16 hi = (_Float16)v;
            _Float16 lo = (_Float16)(v - (float)hi);
            Whi[(size_t)r * 768 + c] = hi;
            Wlo[(size_t)r * 768 + c] = lo;
        }
    } else if (bid < 1280) {
        int n = bid - 768;
        if (tid < 128) {
            float v = W_x[(size_t)tid * 512 + n];
            _Float16 hi = (_Float16)v;
            _Float16 lo = (_Float16)(v - (float)hi);
            WxThi[(size_t)n * 128 + tid] = hi;
            WxTlo[(size_t)n * 128 + tid] = lo;
        }
    } else {
        for (int r = tid; r < 512; r += 256) {
            float s = 0.f;
            const float* wm = W_m + (size_t)r * 256;
            for (int i = 0; i < 256; ++i) s += wm[i] * Bv[i];
            wmb[r] = s;
        }
    }
}

// ---------------------------------------------------------------------------
// k_u: u[b][t] = sum_f x[b][t+1][f] * e_x[f]
// ---------------------------------------------------------------------------
__global__ void k_u(const float* __restrict__ x, const float* __restrict__ e_x,
                    float* __restrict__ u) {
    int wave = threadIdx.x >> 6, l = threadIdx.x & 63;
    int t = blockIdx.x * 4 + wave;
    int b = blockIdx.y;
    const float* xr = x + ((size_t)b * 1025 + t + 1) * 128;
    float s = xr[2 * l] * e_x[2 * l] + xr[2 * l + 1] * e_x[2 * l + 1];
#pragma unroll
    for (int off = 1; off < 64; off <<= 1) s += __shfl_xor(s, off);
    if (l == 0) u[(size_t)b * 1024 + t] = s;
}

// ---------------------------------------------------------------------------
// k_pre: d_out[b][t][n] = sum_f x[b][t+1][f] * W_x[f][n]   (fp16 3-split MFMA)
// grid (1024 Mblocks of 64, 2 Nblocks of 256), block 256 (4 waves = M-tiles)
// ---------------------------------------------------------------------------
__global__ __launch_bounds__(256, 1) void k_pre(const float* __restrict__ x,
                                                const _Float16* __restrict__ WxThi,
                                                const _Float16* __restrict__ WxTlo,
                                                float* __restrict__ out) {
    __shared__ float xt[64][132];
    int tid = threadIdx.x;
    int Mb = blockIdx.x, Nb = blockIdx.y;
    int b = (Mb * 64) >> 10;
    int t0 = (Mb * 64) & 1023;
    const float* src = x + ((size_t)b * 1025 + t0 + 1) * 128;
#pragma unroll
    for (int i = 0; i < 8; ++i) {
        int idx = tid + i * 256;
        int row = idx >> 5, c4 = (idx & 31) * 4;
        *(f32x4*)&xt[row][c4] = *(const f32x4*)(src + (size_t)row * 128 + c4);
    }
    __syncthreads();

    int wave = tid >> 6, l = tid & 63;
    int kg = (l >> 4) * 4;
    int mrow = wave * 16 + (l & 15);

    half8 ah[4], al[4];
#pragma unroll
    for (int kt = 0; kt < 4; ++kt) {
        f32x4 f0 = *(const f32x4*)&xt[mrow][kt * 32 + kg];
        f32x4 f1 = *(const f32x4*)&xt[mrow][kt * 32 + kg + 16];
        H8 hh, ll;
#pragma unroll
        for (int e = 0; e < 4; ++e) {
            _Float16 h0 = (_Float16)f0[e];
            ((_Float16*)&hh)[e] = h0;
            ((_Float16*)&ll)[e] = (_Float16)(f0[e] - (float)h0);
            _Float16 h1 = (_Float16)f1[e];
            ((_Float16*)&hh)[e + 4] = h1;
            ((_Float16*)&ll)[e + 4] = (_Float16)(f1[e] - (float)h1);
        }
        ah[kt] = hh.h;
        al[kt] = ll.h;
    }

    f32x4 acc[16];
#pragma unroll
    for (int nt = 0; nt < 16; ++nt) acc[nt] = (f32x4)0.f;

#pragma unroll
    for (int nt = 0; nt < 16; ++nt) {
        size_t nrow = (size_t)(Nb * 256 + nt * 16 + (l & 15));
#pragma unroll
        for (int kt = 0; kt < 4; ++kt) {
            size_t base = nrow * 128 + kt * 32 + kg;
            half8 bh = load_w_frag(WxThi, base);
            half8 bl = load_w_frag(WxTlo, base);
            acc[nt] = MFMA16(ah[kt], bh, acc[nt]);
            acc[nt] = MFMA16(al[kt], bh, acc[nt]);
            acc[nt] = MFMA16(ah[kt], bl, acc[nt]);
        }
    }

#pragma unroll
    for (int nt = 0; nt < 16; ++nt) {
#pragma unroll
        for (int r = 0; r < 4; ++r) {
            size_t bt = (size_t)Mb * 64 + wave * 16 + 4 * (l >> 4) + r;
            out[bt * 512 + Nb * 256 + nt * 16 + (l & 15)] = acc[nt][r];
        }
    }
}

// ---------------------------------------------------------------------------
// k_seq: the sequential recurrence.
// 48 WGs x 512 thr. WG = (group g, rank). ranks 0..7: h-rows (K=768, NKT=3/wave),
// ranks 8..11: m-rows (K=256, NKT=1/wave). 8 waves K-split, LDS partial reduce.
// ---------------------------------------------------------------------------
#define STATE_U32 (64 * 768)

template <int NKT>
__device__ __forceinline__ void seq_body(int g, int rank, int rowBase, int kbase,
                                         int wave, int l,
                                         const _Float16* __restrict__ Whi,
                                         const _Float16* __restrict__ Wlo,
                                         const float* __restrict__ wmb,
                                         const float* __restrict__ uarr,
                                         const float* __restrict__ Bv,
                                         unsigned int* sbuf, int* arrive,
                                         float* out, f32x4 (*pscr)[4][64]) {
    constexpr bool isH = (NKT == 3);
    int kg = (l >> 4) * 4;

    // ---- load weight fragments into registers (once) ----
    half8 Bh[4][NKT], Bl[4][NKT];
#pragma unroll
    for (int nt = 0; nt < 4; ++nt) {
#pragma unroll
        for (int kt = 0; kt < NKT; ++kt) {
            size_t base = (size_t)(rowBase + nt * 16 + (l & 15)) * 768 + kbase + kt * 32 + kg;
            Bh[nt][kt] = load_w_frag(Whi, base);
            Bl[nt][kt] = load_w_frag(Wlo, base);
        }
    }

    int frow = rowBase + wave * 16 + (l & 15);  // finish row (wave<4 only)
    float coefU = 0.f;
    if (wave < 4) coefU = isH ? wmb[frow] : Bv[frow - 512];

    int bA = g * 16 + (l & 15);  // A-operand batch row

    for (int t = 1; t <= 1024; ++t) {
        // ---- wait until all 12 WGs of this group finished step t-1 ----
        {
            int fidx = g * 16 + (l % 12);
            for (;;) {
                int a = __hip_atomic_load(&arrive[fidx], __ATOMIC_ACQUIRE,
                                          __HIP_MEMORY_SCOPE_AGENT);
                if (__all(a >= 4 * (t - 1))) break;
                __builtin_amdgcn_s_sleep(1);
            }
        }

        // ---- prefetch finish operands (off critical MFMA path) ----
        float pxw[4], uv[4];
        if (wave < 4) {
#pragma unroll
            for (int r = 0; r < 4; ++r) {
                int bG = g * 16 + 4 * (l >> 4) + r;
                uv[r] = uarr[(size_t)bG * 1024 + (t - 1)];
                if (isH)
                    pxw[r] = out[(((size_t)bG << 10) + (t - 1)) * 512 + frow];
            }
        }

        // ---- A loads (state t-1) + MFMA ----
        const unsigned int* rb = sbuf + (size_t)((t - 1) & 1) * STATE_U32;
        f32x4 acc[4];
#pragma unroll
        for (int nt = 0; nt < 4; ++nt) acc[nt] = (f32x4)0.f;

#pragma unroll
        for (int kt = 0; kt < NKT; ++kt) {
            int k0 = kbase + kt * 32 + kg;
            unsigned long long* pq =
                (unsigned long long*)(rb + (size_t)bA * 768 + k0);
            unsigned long long q0 = __hip_atomic_load(pq + 0, __ATOMIC_RELAXED,
                                                      __HIP_MEMORY_SCOPE_AGENT);
            unsigned long long q1 = __hip_atomic_load(pq + 1, __ATOMIC_RELAXED,
                                                      __HIP_MEMORY_SCOPE_AGENT);
            unsigned long long q2 = __hip_atomic_load(pq + 8, __ATOMIC_RELAXED,
                                                      __HIP_MEMORY_SCOPE_AGENT);
            unsigned long long q3 = __hip_atomic_load(pq + 9, __ATOMIC_RELAXED,
                                                      __HIP_MEMORY_SCOPE_AGENT);
            half8 Ah, Al;
            unpack_state(q0, q1, q2, q3, Ah, Al);
#pragma unroll
            for (int nt = 0; nt < 4; ++nt) {
                acc[nt] = MFMA16(Ah, Bh[nt][kt], acc[nt]);
                acc[nt] = MFMA16(Al, Bh[nt][kt], acc[nt]);
                acc[nt] = MFMA16(Ah, Bl[nt][kt], acc[nt]);
            }
        }

        // ---- partial sums to LDS ----
#pragma unroll
        for (int nt = 0; nt < 4; ++nt) pscr[wave][nt][l] = acc[nt];
        __syncthreads();

        // ---- reduce + finish (waves 0..3, wave == nt) ----
        if (wave < 4) {
            f32x4 s = pscr[0][wave][l];
#pragma unroll
            for (int w = 1; w < 8; ++w) s += pscr[w][wave][l];

            unsigned int* wb = sbuf + (size_t)(t & 1) * STATE_U32;
#pragma unroll
            for (int r = 0; r < 4; ++r) {
                int bG = g * 16 + 4 * (l >> 4) + r;
                float v = s[r] + coefU * uv[r];
                if (isH) {
                    v += pxw[r];
                    v = (v >= 0.f) ? v : 0.2f * v;
                    out[(((size_t)bG << 10) + (t - 1)) * 512 + frow] = v;
                }
                _Float16 hi = (_Float16)v;
                _Float16 lo = (_Float16)(v - (float)hi);
                unsigned int pr = (unsigned int)__builtin_bit_cast(unsigned short, hi) |
                                  ((unsigned int)__builtin_bit_cast(unsigned short, lo) << 16);
                __hip_atomic_store(&wb[(size_t)bG * 768 + frow], pr, __ATOMIC_RELAXED,
                                   __HIP_MEMORY_SCOPE_AGENT);
            }
            if (l == 0)
                __hip_atomic_fetch_add(&arrive[g * 16 + rank], 1, __ATOMIC_RELEASE,
                                       __HIP_MEMORY_SCOPE_AGENT);
        }
        __syncthreads();  // protects pscr reuse next step
    }
}

__global__ __launch_bounds__(512, 1) void k_seq(const _Float16* __restrict__ Whi,
                                                const _Float16* __restrict__ Wlo,
                                                const float* __restrict__ wmb,
                                                const float* __restrict__ uarr,
                                                const float* __restrict__ Bv,
                                                unsigned int* sbuf, int* arrive,
                                                float* out) {
    __shared__ f32x4 pscr[8][4][64];
    int tid = threadIdx.x;
    int wave = tid >> 6, l = tid & 63;
    int g = blockIdx.x / 12, rank = blockIdx.x % 12;
    if (rank < 8) {
        seq_body<3>(g, rank, rank * 64, wave * 96, wave, l, Whi, Wlo, wmb, uarr, Bv,
                    sbuf, arrive, out, pscr);
    } else {
        seq_body<1>(g, rank, 512 + (rank - 8) * 64, 512 + wave * 32, wave, l, Whi, Wlo,
                    wmb, uarr, Bv, sbuf, arrive, out, pscr);
    }
}

// ---------------------------------------------------------------------------
extern "C" void kernel_launch(void* const* d_in, const int* in_sizes, int n_in,
                              void* d_out, int out_size, void* d_ws, size_t ws_size,
                              hipStream_t stream) {
    const float* x   = (const float*)d_in[0];
    const float* A   = (const float*)d_in[1];
    const float* Bv  = (const float*)d_in[2];
    const float* W_x = (const float*)d_in[3];
    const float* e_x = (const float*)d_in[4];
    const float* W_h = (const float*)d_in[5];
    const float* W_m = (const float*)d_in[6];
    float* out = (float*)d_out;

    char* ws = (char*)d_ws;
    size_t off = 0;
    auto carve = [&](size_t n) -> char* {
        char* p = ws + off;
        off += (n + 255) & ~(size_t)255;
        return p;
    };
    _Float16* Whi   = (_Float16*)carve(768 * 768 * 2);
    _Float16* Wlo   = (_Float16*)carve(768 * 768 * 2);
    _Float16* WxThi = (_Float16*)carve(512 * 128 * 2);
    _Float16* WxTlo = (_Float16*)carve(512 * 128 * 2);
    float* wmb      = (float*)carve(512 * 4);
    float* u        = (float*)carve(64 * 1024 * 4);
    unsigned int* sbuf = (unsigned int*)carve(2 * STATE_U32 * 4);
    int* arrive     = (int*)carve(256);

    // zero state ping-pong buffers + arrival counters (adjacent)
    hipMemsetAsync(sbuf, 0, (size_t)2 * STATE_U32 * 4 + 256, stream);

    hipLaunchKernelGGL(k_prep, dim3(1281), dim3(256), 0, stream, A, Bv, W_x, W_h, W_m,
                       Whi, Wlo, WxThi, WxTlo, wmb);
    hipLaunchKernelGGL(k_u, dim3(256, 64), dim3(256), 0, stream, x, e_x, u);
    hipLaunchKernelGGL(k_pre, dim3(1024, 2), dim3(256), 0, stream, x, WxThi, WxTlo, out);

    void* args[] = {(void*)&Whi, (void*)&Wlo, (void*)&wmb, (void*)&u,
                    (void*)&Bv,  (void*)&sbuf, (void*)&arrive, (void*)&out};
    hipLaunchCooperativeKernel((void*)k_seq, dim3(48), dim3(512), args, 0, stream);
}

// Round 2
// 8511.762 us; speedup vs baseline: 1.3973x; 1.3973x over previous
//
#include <hip/hip_runtime.h>
#include <stdint.h>

// ---------------------------------------------------------------------------
// KerasLMU fused recurrence:
//   state s = [h(512) ; m(256)],  BigW = [[W_h | W_m@A],[0 | A]]  (768x768)
//   s_t = act( pre_t + BigW @ s_{t-1} ),  act = leakyrelu on h-rows, identity on m-rows
//   pre_t = [ xW_x + (W_m b) u_t ; b u_t ]
// Sequential kernel: 4 groups x 16 batches, 12 WGs/group (8 h-WGs, 4 m-WGs),
// fp16 3-term-split MFMA (16x16x32), weights in VGPRs.
// R1 sync redesign: single-wave relaxed polling (no acquire/buffer_inv storm),
// zero RMWs (per-finish-wave release STORE of step number), out-stores off the
// critical path, per-group flag lines padded.
// ---------------------------------------------------------------------------

typedef _Float16 half8 __attribute__((ext_vector_type(8)));
typedef float f32x4 __attribute__((ext_vector_type(4)));

union H8 {
    half8 h;
    unsigned int u[4];
};

__device__ __forceinline__ half8 load_w_frag(const _Float16* W, size_t base) {
    // elems 0..3 = k..k+3, elems 4..7 = k+16..k+19
    H8 r;
    const unsigned int* p0 = (const unsigned int*)(W + base);
    const unsigned int* p1 = (const unsigned int*)(W + base + 16);
    r.u[0] = p0[0]; r.u[1] = p0[1];
    r.u[2] = p1[0]; r.u[3] = p1[1];
    return r.h;
}

__device__ __forceinline__ void unpack_state(unsigned long long q0, unsigned long long q1,
                                             unsigned long long q2, unsigned long long q3,
                                             half8& hi, half8& lo) {
    unsigned int a0 = (unsigned int)q0, a1 = (unsigned int)(q0 >> 32);
    unsigned int b0 = (unsigned int)q1, b1 = (unsigned int)(q1 >> 32);
    unsigned int c0 = (unsigned int)q2, c1 = (unsigned int)(q2 >> 32);
    unsigned int d0 = (unsigned int)q3, d1 = (unsigned int)(q3 >> 32);
    H8 h, l;
    h.u[0] = (a0 & 0xffffu) | (a1 << 16);  l.u[0] = (a0 >> 16) | (a1 & 0xffff0000u);
    h.u[1] = (b0 & 0xffffu) | (b1 << 16);  l.u[1] = (b0 >> 16) | (b1 & 0xffff0000u);
    h.u[2] = (c0 & 0xffffu) | (c1 << 16);  l.u[2] = (c0 >> 16) | (c1 & 0xffff0000u);
    h.u[3] = (d0 & 0xffffu) | (d1 << 16);  l.u[3] = (d0 >> 16) | (d1 & 0xffff0000u);
    hi = h.h; lo = l.h;
}

#define MFMA16(a, b, c) __builtin_amdgcn_mfma_f32_16x16x32_f16((a), (b), (c), 0, 0, 0)

// ---------------------------------------------------------------------------
// k_prep: build BigW fp16 splits (768x768), WxT splits (512x128), wmb (512)
// ---------------------------------------------------------------------------
__global__ void k_prep(const float* __restrict__ A, const float* __restrict__ Bv,
                       const float* __restrict__ W_x, const float* __restrict__ W_h,
                       const float* __restrict__ W_m,
                       _Float16* __restrict__ Whi, _Float16* __restrict__ Wlo,
                       _Float16* __restrict__ WxThi, _Float16* __restrict__ WxTlo,
                       float* __restrict__ wmb) {
    int bid = blockIdx.x, tid = threadIdx.x;
    if (bid < 768) {
        int r = bid;
        for (int c = tid; c < 768; c += 256) {
            float v;
            if (r < 512) {
                if (c < 512) {
                    v = W_h[(size_t)r * 512 + c];
                } else {
                    float s = 0.f;
                    const float* wm = W_m + (size_t)r * 256;
                    int j = c - 512;
                    for (int i = 0; i < 256; ++i) s += wm[i] * A[(size_t)i * 256 + j];
                    v = s;
                }
            } else {
                v = (c < 512) ? 0.f : A[(size_t)(r - 512) * 256 + (c - 512)];
            }
            _Float16 hi = (_Float16)v;
            _Float16 lo = (_Float16)(v - (float)hi);
            Whi[(size_t)r * 768 + c] = hi;
            Wlo[(size_t)r * 768 + c] = lo;
        }
    } else if (bid < 1280) {
        int n = bid - 768;
        if (tid < 128) {
            float v = W_x[(size_t)tid * 512 + n];
            _Float16 hi = (_Float16)v;
            _Float16 lo = (_Float16)(v - (float)hi);
            WxThi[(size_t)n * 128 + tid] = hi;
            WxTlo[(size_t)n * 128 + tid] = lo;
        }
    } else {
        for (int r = tid; r < 512; r += 256) {
            float s = 0.f;
            const float* wm = W_m + (size_t)r * 256;
            for (int i = 0; i < 256; ++i) s += wm[i] * Bv[i];
            wmb[r] = s;
        }
    }
}

// ---------------------------------------------------------------------------
// k_u: u[b][t] = sum_f x[b][t+1][f] * e_x[f]
// ---------------------------------------------------------------------------
__global__ void k_u(const float* __restrict__ x, const float* __restrict__ e_x,
                    float* __restrict__ u) {
    int wave = threadIdx.x >> 6, l = threadIdx.x & 63;
    int t = blockIdx.x * 4 + wave;
    int b = blockIdx.y;
    const float* xr = x + ((size_t)b * 1025 + t + 1) * 128;
    float s = xr[2 * l] * e_x[2 * l] + xr[2 * l + 1] * e_x[2 * l + 1];
#pragma unroll
    for (int off = 1; off < 64; off <<= 1) s += __shfl_xor(s, off);
    if (l == 0) u[(size_t)b * 1024 + t] = s;
}

// ---------------------------------------------------------------------------
// k_pre: d_out[b][t][n] = sum_f x[b][t+1][f] * W_x[f][n]   (fp16 3-split MFMA)
// ---------------------------------------------------------------------------
__global__ __launch_bounds__(256, 1) void k_pre(const float* __restrict__ x,
                                                const _Float16* __restrict__ WxThi,
                                                const _Float16* __restrict__ WxTlo,
                                                float* __restrict__ out) {
    __shared__ float xt[64][132];
    int tid = threadIdx.x;
    int Mb = blockIdx.x, Nb = blockIdx.y;
    int b = (Mb * 64) >> 10;
    int t0 = (Mb * 64) & 1023;
    const float* src = x + ((size_t)b * 1025 + t0 + 1) * 128;
#pragma unroll
    for (int i = 0; i < 8; ++i) {
        int idx = tid + i * 256;
        int row = idx >> 5, c4 = (idx & 31) * 4;
        *(f32x4*)&xt[row][c4] = *(const f32x4*)(src + (size_t)row * 128 + c4);
    }
    __syncthreads();

    int wave = tid >> 6, l = tid & 63;
    int kg = (l >> 4) * 4;
    int mrow = wave * 16 + (l & 15);

    half8 ah[4], al[4];
#pragma unroll
    for (int kt = 0; kt < 4; ++kt) {
        f32x4 f0 = *(const f32x4*)&xt[mrow][kt * 32 + kg];
        f32x4 f1 = *(const f32x4*)&xt[mrow][kt * 32 + kg + 16];
        H8 hh, ll;
#pragma unroll
        for (int e = 0; e < 4; ++e) {
            _Float16 h0 = (_Float16)f0[e];
            ((_Float16*)&hh)[e] = h0;
            ((_Float16*)&ll)[e] = (_Float16)(f0[e] - (float)h0);
            _Float16 h1 = (_Float16)f1[e];
            ((_Float16*)&hh)[e + 4] = h1;
            ((_Float16*)&ll)[e + 4] = (_Float16)(f1[e] - (float)h1);
        }
        ah[kt] = hh.h;
        al[kt] = ll.h;
    }

    f32x4 acc[16];
#pragma unroll
    for (int nt = 0; nt < 16; ++nt) acc[nt] = (f32x4)0.f;

#pragma unroll
    for (int nt = 0; nt < 16; ++nt) {
        size_t nrow = (size_t)(Nb * 256 + nt * 16 + (l & 15));
#pragma unroll
        for (int kt = 0; kt < 4; ++kt) {
            size_t base = nrow * 128 + kt * 32 + kg;
            half8 bh = load_w_frag(WxThi, base);
            half8 bl = load_w_frag(WxTlo, base);
            acc[nt] = MFMA16(ah[kt], bh, acc[nt]);
            acc[nt] = MFMA16(al[kt], bh, acc[nt]);
            acc[nt] = MFMA16(ah[kt], bl, acc[nt]);
        }
    }

#pragma unroll
    for (int nt = 0; nt < 16; ++nt) {
#pragma unroll
        for (int r = 0; r < 4; ++r) {
            size_t bt = (size_t)Mb * 64 + wave * 16 + 4 * (l >> 4) + r;
            out[bt * 512 + Nb * 256 + nt * 16 + (l & 15)] = acc[nt][r];
        }
    }
}

// ---------------------------------------------------------------------------
// k_seq: the sequential recurrence.
// 48 WGs x 512 thr. WG = (group g, rank). ranks 0..7: h-rows (K=768, NKT=3/wave),
// ranks 8..11: m-rows (K=256, NKT=1/wave). 8 waves K-split, LDS partial reduce.
// Flags: flags[g*64 + rank*4 + w] = last step finished by finish-wave w of rank.
// ---------------------------------------------------------------------------
#define STATE_U32 (64 * 768)

template <int NKT>
__device__ __forceinline__ void seq_body(int g, int rank, int rowBase, int kbase,
                                         int wave, int l,
                                         const _Float16* __restrict__ Whi,
                                         const _Float16* __restrict__ Wlo,
                                         const float* __restrict__ wmb,
                                         const float* __restrict__ uarr,
                                         const float* __restrict__ Bv,
                                         unsigned int* sbuf, int* flags,
                                         float* out, f32x4 (*pscr)[4][64]) {
    constexpr bool isH = (NKT == 3);
    int kg = (l >> 4) * 4;

    // ---- load weight fragments into registers (once) ----
    half8 Bh[4][NKT], Bl[4][NKT];
#pragma unroll
    for (int nt = 0; nt < 4; ++nt) {
#pragma unroll
        for (int kt = 0; kt < NKT; ++kt) {
            size_t base = (size_t)(rowBase + nt * 16 + (l & 15)) * 768 + kbase + kt * 32 + kg;
            Bh[nt][kt] = load_w_frag(Whi, base);
            Bl[nt][kt] = load_w_frag(Wlo, base);
        }
    }

    int frow = rowBase + wave * 16 + (l & 15);  // finish row (wave<4 only)
    float coefU = 0.f;
    if (wave < 4) coefU = isH ? wmb[frow] : Bv[frow - 512];

    int bA = g * 16 + (l & 15);  // A-operand batch row
    int* gflags = flags + g * 64;

    for (int t = 1; t <= 1024; ++t) {
        // ---- prefetch finish operands (independent of flags) ----
        float pxw[4], uv[4];
        if (wave < 4) {
#pragma unroll
            for (int r = 0; r < 4; ++r) {
                int bG = g * 16 + 4 * (l >> 4) + r;
                uv[r] = uarr[(size_t)bG * 1024 + (t - 1)];
                if (isH)
                    pxw[r] = out[(((size_t)bG << 10) + (t - 1)) * 512 + frow];
            }
        }

        // ---- single wave polls 48 flags with RELAXED loads ----
        if (wave == 7) {
            for (;;) {
                int a = 0x7fffffff;
                if (l < 48)
                    a = __hip_atomic_load(&gflags[l], __ATOMIC_RELAXED,
                                          __HIP_MEMORY_SCOPE_AGENT);
                if (__all(a >= t - 1)) break;
                __builtin_amdgcn_s_sleep(2);
            }
        }
        __syncthreads();  // releases all waves once step t-1 fully published

        // ---- A loads (state t-1) + MFMA ----
        const unsigned int* rb = sbuf + (size_t)((t - 1) & 1) * STATE_U32;
        f32x4 acc[4];
#pragma unroll
        for (int nt = 0; nt < 4; ++nt) acc[nt] = (f32x4)0.f;

#pragma unroll
        for (int kt = 0; kt < NKT; ++kt) {
            int k0 = kbase + kt * 32 + kg;
            unsigned long long* pq =
                (unsigned long long*)(rb + (size_t)bA * 768 + k0);
            unsigned long long q0 = __hip_atomic_load(pq + 0, __ATOMIC_RELAXED,
                                                      __HIP_MEMORY_SCOPE_AGENT);
            unsigned long long q1 = __hip_atomic_load(pq + 1, __ATOMIC_RELAXED,
                                                      __HIP_MEMORY_SCOPE_AGENT);
            unsigned long long q2 = __hip_atomic_load(pq + 8, __ATOMIC_RELAXED,
                                                      __HIP_MEMORY_SCOPE_AGENT);
            unsigned long long q3 = __hip_atomic_load(pq + 9, __ATOMIC_RELAXED,
                                                      __HIP_MEMORY_SCOPE_AGENT);
            half8 Ah, Al;
            unpack_state(q0, q1, q2, q3, Ah, Al);
#pragma unroll
            for (int nt = 0; nt < 4; ++nt) {
                acc[nt] = MFMA16(Ah, Bh[nt][kt], acc[nt]);
                acc[nt] = MFMA16(Al, Bh[nt][kt], acc[nt]);
                acc[nt] = MFMA16(Ah, Bl[nt][kt], acc[nt]);
            }
        }

        // ---- partial sums to LDS ----
#pragma unroll
        for (int nt = 0; nt < 4; ++nt) pscr[wave][nt][l] = acc[nt];
        __syncthreads();

        // ---- reduce + finish (waves 0..3, wave == nt) ----
        if (wave < 4) {
            f32x4 s = pscr[0][wave][l];
#pragma unroll
            for (int w = 1; w < 8; ++w) s += pscr[w][wave][l];

            unsigned int* wb = sbuf + (size_t)(t & 1) * STATE_U32;
            float vout[4];
#pragma unroll
            for (int r = 0; r < 4; ++r) {
                int bG = g * 16 + 4 * (l >> 4) + r;
                float v = s[r] + coefU * uv[r];
                if (isH) {
                    v += pxw[r];
                    v = (v >= 0.f) ? v : 0.2f * v;
                }
                vout[r] = v;
                _Float16 hi = (_Float16)v;
                _Float16 lo = (_Float16)(v - (float)hi);
                unsigned int pr = (unsigned int)__builtin_bit_cast(unsigned short, hi) |
                                  ((unsigned int)__builtin_bit_cast(unsigned short, lo) << 16);
                __hip_atomic_store(&wb[(size_t)bG * 768 + frow], pr, __ATOMIC_RELAXED,
                                   __HIP_MEMORY_SCOPE_AGENT);
            }
            // Release: waits vmcnt(0) (this wave's state stores), then sc1 store.
            __hip_atomic_store(&gflags[rank * 4 + wave], t, __ATOMIC_RELEASE,
                               __HIP_MEMORY_SCOPE_AGENT);
            // Output stores AFTER the flag — off the critical sync path.
            if (isH) {
#pragma unroll
                for (int r = 0; r < 4; ++r) {
                    int bG = g * 16 + 4 * (l >> 4) + r;
                    out[(((size_t)bG << 10) + (t - 1)) * 512 + frow] = vout[r];
                }
            }
        }
        // No end-of-step barrier needed: pscr is only rewritten after the next
        // poll-barrier, and state buffer (t+1)&1 is only written after the next
        // poll confirms every WG finished step t (i.e. stopped reading it).
    }
}

__global__ __launch_bounds__(512, 1) void k_seq(const _Float16* __restrict__ Whi,
                                                const _Float16* __restrict__ Wlo,
                                                const float* __restrict__ wmb,
                                                const float* __restrict__ uarr,
                                                const float* __restrict__ Bv,
                                                unsigned int* sbuf, int* flags,
                                                float* out) {
    __shared__ f32x4 pscr[8][4][64];
    int tid = threadIdx.x;
    int wave = tid >> 6, l = tid & 63;
    int g = blockIdx.x / 12, rank = blockIdx.x % 12;
    if (rank < 8) {
        seq_body<3>(g, rank, rank * 64, wave * 96, wave, l, Whi, Wlo, wmb, uarr, Bv,
                    sbuf, flags, out, pscr);
    } else {
        seq_body<1>(g, rank, 512 + (rank - 8) * 64, 512 + wave * 32, wave, l, Whi, Wlo,
                    wmb, uarr, Bv, sbuf, flags, out, pscr);
    }
}

// ---------------------------------------------------------------------------
extern "C" void kernel_launch(void* const* d_in, const int* in_sizes, int n_in,
                              void* d_out, int out_size, void* d_ws, size_t ws_size,
                              hipStream_t stream) {
    const float* x   = (const float*)d_in[0];
    const float* A   = (const float*)d_in[1];
    const float* Bv  = (const float*)d_in[2];
    const float* W_x = (const float*)d_in[3];
    const float* e_x = (const float*)d_in[4];
    const float* W_h = (const float*)d_in[5];
    const float* W_m = (const float*)d_in[6];
    float* out = (float*)d_out;

    char* ws = (char*)d_ws;
    size_t off = 0;
    auto carve = [&](size_t n) -> char* {
        char* p = ws + off;
        off += (n + 255) & ~(size_t)255;
        return p;
    };
    _Float16* Whi   = (_Float16*)carve(768 * 768 * 2);
    _Float16* Wlo   = (_Float16*)carve(768 * 768 * 2);
    _Float16* WxThi = (_Float16*)carve(512 * 128 * 2);
    _Float16* WxTlo = (_Float16*)carve(512 * 128 * 2);
    float* wmb      = (float*)carve(512 * 4);
    float* u        = (float*)carve(64 * 1024 * 4);
    unsigned int* sbuf = (unsigned int*)carve(2 * STATE_U32 * 4);
    int* flags      = (int*)carve(4 * 64 * 4);  // 4 groups x 64 ints (256B apart)

    // zero state ping-pong buffers + flags (adjacent in ws)
    hipMemsetAsync(sbuf, 0, (size_t)2 * STATE_U32 * 4 + 4 * 64 * 4, stream);

    hipLaunchKernelGGL(k_prep, dim3(1281), dim3(256), 0, stream, A, Bv, W_x, W_h, W_m,
                       Whi, Wlo, WxThi, WxTlo, wmb);
    hipLaunchKernelGGL(k_u, dim3(256, 64), dim3(256), 0, stream, x, e_x, u);
    hipLaunchKernelGGL(k_pre, dim3(1024, 2), dim3(256), 0, stream, x, WxThi, WxTlo, out);

    void* args[] = {(void*)&Whi, (void*)&Wlo, (void*)&wmb, (void*)&u,
                    (void*)&Bv,  (void*)&sbuf, (void*)&flags, (void*)&out};
    hipLaunchCooperativeKernel((void*)k_seq, dim3(48), dim3(512), args, 0, stream);
}

// Round 3
// 5851.864 us; speedup vs baseline: 2.0324x; 1.4545x over previous
//
#include <hip/hip_runtime.h>
#include <stdint.h>

// ---------------------------------------------------------------------------
// KerasLMU fused recurrence:
//   state s = [h(512) ; m(256)],  BigW = [[W_h | W_m@A],[0 | A]]  (768x768)
//   s_t = act( pre_t + BigW @ s_{t-1} ),  act = leakyrelu on h-rows, identity on m-rows
//   pre_t = [ xW_x + (W_m b) u_t ; b u_t ]
// Sequential kernel: 4 groups x 16 batches, 12 WGs/group (8 h-WGs, 4 m-WGs),
// fp16 3-term-split MFMA (16x16x32), weights in VGPRs.
// R2->R3: manual release (s_waitcnt vmcnt(0) + RELAXED flag store) instead of
// __ATOMIC_RELEASE -- the C++ release lowers to buffer_wbl2 (full L2 dirty
// writeback) on the critical path of every finish wave every step. Also batch
// all state loads before unpack/MFMA (single LLC-latency exposure).
// ---------------------------------------------------------------------------

typedef _Float16 half8 __attribute__((ext_vector_type(8)));
typedef float f32x4 __attribute__((ext_vector_type(4)));

union H8 {
    half8 h;
    unsigned int u[4];
};

__device__ __forceinline__ half8 load_w_frag(const _Float16* W, size_t base) {
    // elems 0..3 = k..k+3, elems 4..7 = k+16..k+19
    H8 r;
    const unsigned int* p0 = (const unsigned int*)(W + base);
    const unsigned int* p1 = (const unsigned int*)(W + base + 16);
    r.u[0] = p0[0]; r.u[1] = p0[1];
    r.u[2] = p1[0]; r.u[3] = p1[1];
    return r.h;
}

__device__ __forceinline__ void unpack_state(unsigned long long q0, unsigned long long q1,
                                             unsigned long long q2, unsigned long long q3,
                                             half8& hi, half8& lo) {
    unsigned int a0 = (unsigned int)q0, a1 = (unsigned int)(q0 >> 32);
    unsigned int b0 = (unsigned int)q1, b1 = (unsigned int)(q1 >> 32);
    unsigned int c0 = (unsigned int)q2, c1 = (unsigned int)(q2 >> 32);
    unsigned int d0 = (unsigned int)q3, d1 = (unsigned int)(q3 >> 32);
    H8 h, l;
    h.u[0] = (a0 & 0xffffu) | (a1 << 16);  l.u[0] = (a0 >> 16) | (a1 & 0xffff0000u);
    h.u[1] = (b0 & 0xffffu) | (b1 << 16);  l.u[1] = (b0 >> 16) | (b1 & 0xffff0000u);
    h.u[2] = (c0 & 0xffffu) | (c1 << 16);  l.u[2] = (c0 >> 16) | (c1 & 0xffff0000u);
    h.u[3] = (d0 & 0xffffu) | (d1 << 16);  l.u[3] = (d0 >> 16) | (d1 & 0xffff0000u);
    hi = h.h; lo = l.h;
}

#define MFMA16(a, b, c) __builtin_amdgcn_mfma_f32_16x16x32_f16((a), (b), (c), 0, 0, 0)

#define ALOAD(p) __hip_atomic_load((p), __ATOMIC_RELAXED, __HIP_MEMORY_SCOPE_AGENT)

// ---------------------------------------------------------------------------
// k_prep: build BigW fp16 splits (768x768), WxT splits (512x128), wmb (512)
// ---------------------------------------------------------------------------
__global__ void k_prep(const float* __restrict__ A, const float* __restrict__ Bv,
                       const float* __restrict__ W_x, const float* __restrict__ W_h,
                       const float* __restrict__ W_m,
                       _Float16* __restrict__ Whi, _Float16* __restrict__ Wlo,
                       _Float16* __restrict__ WxThi, _Float16* __restrict__ WxTlo,
                       float* __restrict__ wmb) {
    int bid = blockIdx.x, tid = threadIdx.x;
    if (bid < 768) {
        int r = bid;
        for (int c = tid; c < 768; c += 256) {
            float v;
            if (r < 512) {
                if (c < 512) {
                    v = W_h[(size_t)r * 512 + c];
                } else {
                    float s = 0.f;
                    const float* wm = W_m + (size_t)r * 256;
                    int j = c - 512;
                    for (int i = 0; i < 256; ++i) s += wm[i] * A[(size_t)i * 256 + j];
                    v = s;
                }
            } else {
                v = (c < 512) ? 0.f : A[(size_t)(r - 512) * 256 + (c - 512)];
            }
            _Float16 hi = (_Float16)v;
            _Float16 lo = (_Float16)(v - (float)hi);
            Whi[(size_t)r * 768 + c] = hi;
            Wlo[(size_t)r * 768 + c] = lo;
        }
    } else if (bid < 1280) {
        int n = bid - 768;
        if (tid < 128) {
            float v = W_x[(size_t)tid * 512 + n];
            _Float16 hi = (_Float16)v;
            _Float16 lo = (_Float16)(v - (float)hi);
            WxThi[(size_t)n * 128 + tid] = hi;
            WxTlo[(size_t)n * 128 + tid] = lo;
        }
    } else {
        for (int r = tid; r < 512; r += 256) {
            float s = 0.f;
            const float* wm = W_m + (size_t)r * 256;
            for (int i = 0; i < 256; ++i) s += wm[i] * Bv[i];
            wmb[r] = s;
        }
    }
}

// ---------------------------------------------------------------------------
// k_u: u[b][t] = sum_f x[b][t+1][f] * e_x[f]
// ---------------------------------------------------------------------------
__global__ void k_u(const float* __restrict__ x, const float* __restrict__ e_x,
                    float* __restrict__ u) {
    int wave = threadIdx.x >> 6, l = threadIdx.x & 63;
    int t = blockIdx.x * 4 + wave;
    int b = blockIdx.y;
    const float* xr = x + ((size_t)b * 1025 + t + 1) * 128;
    float s = xr[2 * l] * e_x[2 * l] + xr[2 * l + 1] * e_x[2 * l + 1];
#pragma unroll
    for (int off = 1; off < 64; off <<= 1) s += __shfl_xor(s, off);
    if (l == 0) u[(size_t)b * 1024 + t] = s;
}

// ---------------------------------------------------------------------------
// k_pre: d_out[b][t][n] = sum_f x[b][t+1][f] * W_x[f][n]   (fp16 3-split MFMA)
// ---------------------------------------------------------------------------
__global__ __launch_bounds__(256, 1) void k_pre(const float* __restrict__ x,
                                                const _Float16* __restrict__ WxThi,
                                                const _Float16* __restrict__ WxTlo,
                                                float* __restrict__ out) {
    __shared__ float xt[64][132];
    int tid = threadIdx.x;
    int Mb = blockIdx.x, Nb = blockIdx.y;
    int b = (Mb * 64) >> 10;
    int t0 = (Mb * 64) & 1023;
    const float* src = x + ((size_t)b * 1025 + t0 + 1) * 128;
#pragma unroll
    for (int i = 0; i < 8; ++i) {
        int idx = tid + i * 256;
        int row = idx >> 5, c4 = (idx & 31) * 4;
        *(f32x4*)&xt[row][c4] = *(const f32x4*)(src + (size_t)row * 128 + c4);
    }
    __syncthreads();

    int wave = tid >> 6, l = tid & 63;
    int kg = (l >> 4) * 4;
    int mrow = wave * 16 + (l & 15);

    half8 ah[4], al[4];
#pragma unroll
    for (int kt = 0; kt < 4; ++kt) {
        f32x4 f0 = *(const f32x4*)&xt[mrow][kt * 32 + kg];
        f32x4 f1 = *(const f32x4*)&xt[mrow][kt * 32 + kg + 16];
        H8 hh, ll;
#pragma unroll
        for (int e = 0; e < 4; ++e) {
            _Float16 h0 = (_Float16)f0[e];
            ((_Float16*)&hh)[e] = h0;
            ((_Float16*)&ll)[e] = (_Float16)(f0[e] - (float)h0);
            _Float16 h1 = (_Float16)f1[e];
            ((_Float16*)&hh)[e + 4] = h1;
            ((_Float16*)&ll)[e + 4] = (_Float16)(f1[e] - (float)h1);
        }
        ah[kt] = hh.h;
        al[kt] = ll.h;
    }

    f32x4 acc[16];
#pragma unroll
    for (int nt = 0; nt < 16; ++nt) acc[nt] = (f32x4)0.f;

#pragma unroll
    for (int nt = 0; nt < 16; ++nt) {
        size_t nrow = (size_t)(Nb * 256 + nt * 16 + (l & 15));
#pragma unroll
        for (int kt = 0; kt < 4; ++kt) {
            size_t base = nrow * 128 + kt * 32 + kg;
            half8 bh = load_w_frag(WxThi, base);
            half8 bl = load_w_frag(WxTlo, base);
            acc[nt] = MFMA16(ah[kt], bh, acc[nt]);
            acc[nt] = MFMA16(al[kt], bh, acc[nt]);
            acc[nt] = MFMA16(ah[kt], bl, acc[nt]);
        }
    }

#pragma unroll
    for (int nt = 0; nt < 16; ++nt) {
#pragma unroll
        for (int r = 0; r < 4; ++r) {
            size_t bt = (size_t)Mb * 64 + wave * 16 + 4 * (l >> 4) + r;
            out[bt * 512 + Nb * 256 + nt * 16 + (l & 15)] = acc[nt][r];
        }
    }
}

// ---------------------------------------------------------------------------
// k_seq: the sequential recurrence.
// 48 WGs x 512 thr. WG = (group g, rank). ranks 0..7: h-rows (K=768, NKT=3/wave),
// ranks 8..11: m-rows (K=256, NKT=1/wave). 8 waves K-split, LDS partial reduce.
// Flags: flags[g*64 + rank*4 + w] = last step finished by finish-wave w of rank.
// ---------------------------------------------------------------------------
#define STATE_U32 (64 * 768)

template <int NKT>
__device__ __forceinline__ void seq_body(int g, int rank, int rowBase, int kbase,
                                         int wave, int l,
                                         const _Float16* __restrict__ Whi,
                                         const _Float16* __restrict__ Wlo,
                                         const float* __restrict__ wmb,
                                         const float* __restrict__ uarr,
                                         const float* __restrict__ Bv,
                                         unsigned int* sbuf, int* flags,
                                         float* out, f32x4 (*pscr)[4][64]) {
    constexpr bool isH = (NKT == 3);
    int kg = (l >> 4) * 4;

    // ---- load weight fragments into registers (once) ----
    half8 Bh[4][NKT], Bl[4][NKT];
#pragma unroll
    for (int nt = 0; nt < 4; ++nt) {
#pragma unroll
        for (int kt = 0; kt < NKT; ++kt) {
            size_t base = (size_t)(rowBase + nt * 16 + (l & 15)) * 768 + kbase + kt * 32 + kg;
            Bh[nt][kt] = load_w_frag(Whi, base);
            Bl[nt][kt] = load_w_frag(Wlo, base);
        }
    }

    int frow = rowBase + wave * 16 + (l & 15);  // finish row (wave<4 only)
    float coefU = 0.f;
    if (wave < 4) coefU = isH ? wmb[frow] : Bv[frow - 512];

    int bA = g * 16 + (l & 15);  // A-operand batch row
    int* gflags = flags + g * 64;

    for (int t = 1; t <= 1024; ++t) {
        // ---- prefetch finish operands (independent of flags) ----
        float pxw[4], uv[4];
        if (wave < 4) {
#pragma unroll
            for (int r = 0; r < 4; ++r) {
                int bG = g * 16 + 4 * (l >> 4) + r;
                uv[r] = uarr[(size_t)bG * 1024 + (t - 1)];
                if (isH)
                    pxw[r] = out[(((size_t)bG << 10) + (t - 1)) * 512 + frow];
            }
        }

        // ---- single wave polls 48 flags with RELAXED loads ----
        if (wave == 7) {
            for (;;) {
                int a = 0x7fffffff;
                if (l < 48)
                    a = ALOAD(&gflags[l]);
                if (__all(a >= t - 1)) break;
                __builtin_amdgcn_s_sleep(1);
            }
        }
        __syncthreads();  // releases all waves once step t-1 fully published

        // ---- A loads (state t-1): issue ALL loads, then unpack+MFMA ----
        const unsigned int* rb = sbuf + (size_t)((t - 1) & 1) * STATE_U32;
        unsigned long long q[NKT][4];
#pragma unroll
        for (int kt = 0; kt < NKT; ++kt) {
            int k0 = kbase + kt * 32 + kg;
            unsigned long long* pq =
                (unsigned long long*)(rb + (size_t)bA * 768 + k0);
            q[kt][0] = ALOAD(pq + 0);
            q[kt][1] = ALOAD(pq + 1);
            q[kt][2] = ALOAD(pq + 8);
            q[kt][3] = ALOAD(pq + 9);
        }

        f32x4 acc[4];
#pragma unroll
        for (int nt = 0; nt < 4; ++nt) acc[nt] = (f32x4)0.f;

#pragma unroll
        for (int kt = 0; kt < NKT; ++kt) {
            half8 Ah, Al;
            unpack_state(q[kt][0], q[kt][1], q[kt][2], q[kt][3], Ah, Al);
#pragma unroll
            for (int nt = 0; nt < 4; ++nt) {
                acc[nt] = MFMA16(Ah, Bh[nt][kt], acc[nt]);
                acc[nt] = MFMA16(Al, Bh[nt][kt], acc[nt]);
                acc[nt] = MFMA16(Ah, Bl[nt][kt], acc[nt]);
            }
        }

        // ---- partial sums to LDS ----
#pragma unroll
        for (int nt = 0; nt < 4; ++nt) pscr[wave][nt][l] = acc[nt];
        __syncthreads();

        // ---- reduce + finish (waves 0..3, wave == nt) ----
        if (wave < 4) {
            f32x4 s = pscr[0][wave][l];
#pragma unroll
            for (int w = 1; w < 8; ++w) s += pscr[w][wave][l];

            unsigned int* wb = sbuf + (size_t)(t & 1) * STATE_U32;
            float vout[4];
#pragma unroll
            for (int r = 0; r < 4; ++r) {
                int bG = g * 16 + 4 * (l >> 4) + r;
                float v = s[r] + coefU * uv[r];
                if (isH) {
                    v += pxw[r];
                    v = (v >= 0.f) ? v : 0.2f * v;
                }
                vout[r] = v;
                _Float16 hi = (_Float16)v;
                _Float16 lo = (_Float16)(v - (float)hi);
                unsigned int pr = (unsigned int)__builtin_bit_cast(unsigned short, hi) |
                                  ((unsigned int)__builtin_bit_cast(unsigned short, lo) << 16);
                __hip_atomic_store(&wb[(size_t)bG * 768 + frow], pr, __ATOMIC_RELAXED,
                                   __HIP_MEMORY_SCOPE_AGENT);
            }
            // Manual release: drain this wave's sc1 state stores to the
            // coherence point, then publish the flag with a RELAXED store.
            // (A C++ RELEASE here lowers to buffer_wbl2 = full L2 dirty
            // writeback on the critical path -- the R2 bottleneck.)
            asm volatile("s_waitcnt vmcnt(0)" ::: "memory");
            __hip_atomic_store(&gflags[rank * 4 + wave], t, __ATOMIC_RELAXED,
                               __HIP_MEMORY_SCOPE_AGENT);
            // Output stores AFTER the flag — off the critical sync path.
            if (isH) {
#pragma unroll
                for (int r = 0; r < 4; ++r) {
                    int bG = g * 16 + 4 * (l >> 4) + r;
                    out[(((size_t)bG << 10) + (t - 1)) * 512 + frow] = vout[r];
                }
            }
        }
        // No end-of-step barrier needed: pscr is only rewritten after the next
        // poll-barrier, and state buffer (t+1)&1 is only written after the next
        // poll confirms every WG finished step t (i.e. stopped reading it).
    }
}

__global__ __launch_bounds__(512, 1) void k_seq(const _Float16* __restrict__ Whi,
                                                const _Float16* __restrict__ Wlo,
                                                const float* __restrict__ wmb,
                                                const float* __restrict__ uarr,
                                                const float* __restrict__ Bv,
                                                unsigned int* sbuf, int* flags,
                                                float* out) {
    __shared__ f32x4 pscr[8][4][64];
    int tid = threadIdx.x;
    int wave = tid >> 6, l = tid & 63;
    int g = blockIdx.x / 12, rank = blockIdx.x % 12;
    if (rank < 8) {
        seq_body<3>(g, rank, rank * 64, wave * 96, wave, l, Whi, Wlo, wmb, uarr, Bv,
                    sbuf, flags, out, pscr);
    } else {
        seq_body<1>(g, rank, 512 + (rank - 8) * 64, 512 + wave * 32, wave, l, Whi, Wlo,
                    wmb, uarr, Bv, sbuf, flags, out, pscr);
    }
}

// ---------------------------------------------------------------------------
extern "C" void kernel_launch(void* const* d_in, const int* in_sizes, int n_in,
                              void* d_out, int out_size, void* d_ws, size_t ws_size,
                              hipStream_t stream) {
    const float* x   = (const float*)d_in[0];
    const float* A   = (const float*)d_in[1];
    const float* Bv  = (const float*)d_in[2];
    const float* W_x = (const float*)d_in[3];
    const float* e_x = (const float*)d_in[4];
    const float* W_h = (const float*)d_in[5];
    const float* W_m = (const float*)d_in[6];
    float* out = (float*)d_out;

    char* ws = (char*)d_ws;
    size_t off = 0;
    auto carve = [&](size_t n) -> char* {
        char* p = ws + off;
        off += (n + 255) & ~(size_t)255;
        return p;
    };
    _Float16* Whi   = (_Float16*)carve(768 * 768 * 2);
    _Float16* Wlo   = (_Float16*)carve(768 * 768 * 2);
    _Float16* WxThi = (_Float16*)carve(512 * 128 * 2);
    _Float16* WxTlo = (_Float16*)carve(512 * 128 * 2);
    float* wmb      = (float*)carve(512 * 4);
    float* u        = (float*)carve(64 * 1024 * 4);
    unsigned int* sbuf = (unsigned int*)carve(2 * STATE_U32 * 4);
    int* flags      = (int*)carve(4 * 64 * 4);  // 4 groups x 64 ints (256B apart)

    // zero state ping-pong buffers + flags (adjacent in ws)
    hipMemsetAsync(sbuf, 0, (size_t)2 * STATE_U32 * 4 + 4 * 64 * 4, stream);

    hipLaunchKernelGGL(k_prep, dim3(1281), dim3(256), 0, stream, A, Bv, W_x, W_h, W_m,
                       Whi, Wlo, WxThi, WxTlo, wmb);
    hipLaunchKernelGGL(k_u, dim3(256, 64), dim3(256), 0, stream, x, e_x, u);
    hipLaunchKernelGGL(k_pre, dim3(1024, 2), dim3(256), 0, stream, x, WxThi, WxTlo, out);

    void* args[] = {(void*)&Whi, (void*)&Wlo, (void*)&wmb, (void*)&u,
                    (void*)&Bv,  (void*)&sbuf, (void*)&flags, (void*)&out};
    hipLaunchCooperativeKernel((void*)k_seq, dim3(48), dim3(512), args, 0, stream);
}

// Round 5
// 4473.619 us; speedup vs baseline: 2.6586x; 1.3081x over previous
//
#include <hip/hip_runtime.h>
#include <stdint.h>

// ---------------------------------------------------------------------------
// KerasLMU fused recurrence:
//   state s = [h(512) ; m(256)],  BigW = [[W_h | W_m@A],[0 | A]]  (768x768)
//   s_t = act( pre_t + BigW @ s_{t-1} ),  act = leakyrelu on h-rows, id on m-rows
// R5 = R3's proven agent-scope sync protocol VERBATIM (the R4 XCD-local/sc0
// experiment hung -- reverted) + exactly one new variable:
//   BigW stored FRAGMENT-MAJOR (16B per MFMA fragment) and preloaded via
//   inline-asm dwordx4 -> compiler cannot rematerialize -> truly register-
//   resident weights. (R3 evidence: VGPR_Count=88 < the ~96 regs the weight
//   set needs -> weights were re-loaded from L2 every step on the MFMA path.)
// ---------------------------------------------------------------------------

typedef _Float16 half8 __attribute__((ext_vector_type(8)));
typedef float f32x4 __attribute__((ext_vector_type(4)));
typedef unsigned int u32x4 __attribute__((ext_vector_type(4)));

union H8 { half8 h; unsigned int u[4]; };
union F4 { u32x4 q; half8 h; };

#define MFMA16(a, b, c) __builtin_amdgcn_mfma_f32_16x16x32_f16((a), (b), (c), 0, 0, 0)
#define ALOAD(p) __hip_atomic_load((p), __ATOMIC_RELAXED, __HIP_MEMORY_SCOPE_AGENT)
#define ASTORE(p, v) __hip_atomic_store((p), (v), __ATOMIC_RELAXED, __HIP_MEMORY_SCOPE_AGENT)

__device__ __forceinline__ half8 load_w_frag(const _Float16* W, size_t base) {
    H8 r;
    const unsigned int* p0 = (const unsigned int*)(W + base);
    const unsigned int* p1 = (const unsigned int*)(W + base + 16);
    r.u[0] = p0[0]; r.u[1] = p0[1];
    r.u[2] = p1[0]; r.u[3] = p1[1];
    return r.h;
}

__device__ __forceinline__ void unpack8(u32x4 A, u32x4 B, half8& hi, half8& lo) {
    H8 h, l;
    h.u[0] = (A[0] & 0xffffu) | (A[1] << 16);  l.u[0] = (A[0] >> 16) | (A[1] & 0xffff0000u);
    h.u[1] = (A[2] & 0xffffu) | (A[3] << 16);  l.u[1] = (A[2] >> 16) | (A[3] & 0xffff0000u);
    h.u[2] = (B[0] & 0xffffu) | (B[1] << 16);  l.u[2] = (B[0] >> 16) | (B[1] & 0xffff0000u);
    h.u[3] = (B[2] & 0xffffu) | (B[3] << 16);  l.u[3] = (B[2] >> 16) | (B[3] & 0xffff0000u);
    hi = h.h; lo = l.h;
}

// ---------------------------------------------------------------------------
// k_prep: BigW fp16 splits in FRAGMENT-MAJOR layout:
//   idx(r, cb, kgi, e) = (((r*24 + cb)*4 + kgi)*8 + e), cb = col/32,
//   fragment elems e0..3 = cols cb*32+kgi*4+{0..3}, e4..7 = +16.
// WxT (for k_pre) stays row-major. wmb = W_m @ b.
// ---------------------------------------------------------------------------
__global__ void k_prep(const float* __restrict__ A, const float* __restrict__ Bv,
                       const float* __restrict__ W_x, const float* __restrict__ W_h,
                       const float* __restrict__ W_m,
                       _Float16* __restrict__ Whi, _Float16* __restrict__ Wlo,
                       _Float16* __restrict__ WxThi, _Float16* __restrict__ WxTlo,
                       float* __restrict__ wmb) {
    int bid = blockIdx.x, tid = threadIdx.x;
    if (bid < 768) {
        int r = bid;
        for (int c = tid; c < 768; c += 256) {
            float v;
            if (r < 512) {
                if (c < 512) {
                    v = W_h[(size_t)r * 512 + c];
                } else {
                    float s = 0.f;
                    const float* wm = W_m + (size_t)r * 256;
                    int j = c - 512;
                    for (int i = 0; i < 256; ++i) s += wm[i] * A[(size_t)i * 256 + j];
                    v = s;
                }
            } else {
                v = (c < 512) ? 0.f : A[(size_t)(r - 512) * 256 + (c - 512)];
            }
            _Float16 hi = (_Float16)v;
            _Float16 lo = (_Float16)(v - (float)hi);
            int cb = c >> 5, w = c & 31;
            int kgi = (w & 15) >> 2;
            int e = (w & 3) + ((w & 16) ? 4 : 0);
            size_t idx = (((size_t)r * 24 + cb) * 4 + kgi) * 8 + e;
            Whi[idx] = hi;
            Wlo[idx] = lo;
        }
    } else if (bid < 1280) {
        int n = bid - 768;
        if (tid < 128) {
            float v = W_x[(size_t)tid * 512 + n];
            _Float16 hi = (_Float16)v;
            _Float16 lo = (_Float16)(v - (float)hi);
            WxThi[(size_t)n * 128 + tid] = hi;
            WxTlo[(size_t)n * 128 + tid] = lo;
        }
    } else {
        for (int r = tid; r < 512; r += 256) {
            float s = 0.f;
            const float* wm = W_m + (size_t)r * 256;
            for (int i = 0; i < 256; ++i) s += wm[i] * Bv[i];
            wmb[r] = s;
        }
    }
}

// ---------------------------------------------------------------------------
__global__ void k_u(const float* __restrict__ x, const float* __restrict__ e_x,
                    float* __restrict__ u) {
    int wave = threadIdx.x >> 6, l = threadIdx.x & 63;
    int t = blockIdx.x * 4 + wave;
    int b = blockIdx.y;
    const float* xr = x + ((size_t)b * 1025 + t + 1) * 128;
    float s = xr[2 * l] * e_x[2 * l] + xr[2 * l + 1] * e_x[2 * l + 1];
#pragma unroll
    for (int off = 1; off < 64; off <<= 1) s += __shfl_xor(s, off);
    if (l == 0) u[(size_t)b * 1024 + t] = s;
}

// ---------------------------------------------------------------------------
__global__ __launch_bounds__(256, 1) void k_pre(const float* __restrict__ x,
                                                const _Float16* __restrict__ WxThi,
                                                const _Float16* __restrict__ WxTlo,
                                                float* __restrict__ out) {
    __shared__ float xt[64][132];
    int tid = threadIdx.x;
    int Mb = blockIdx.x, Nb = blockIdx.y;
    int b = (Mb * 64) >> 10;
    int t0 = (Mb * 64) & 1023;
    const float* src = x + ((size_t)b * 1025 + t0 + 1) * 128;
#pragma unroll
    for (int i = 0; i < 8; ++i) {
        int idx = tid + i * 256;
        int row = idx >> 5, c4 = (idx & 31) * 4;
        *(f32x4*)&xt[row][c4] = *(const f32x4*)(src + (size_t)row * 128 + c4);
    }
    __syncthreads();

    int wave = tid >> 6, l = tid & 63;
    int kg = (l >> 4) * 4;
    int mrow = wave * 16 + (l & 15);

    half8 ah[4], al[4];
#pragma unroll
    for (int kt = 0; kt < 4; ++kt) {
        f32x4 f0 = *(const f32x4*)&xt[mrow][kt * 32 + kg];
        f32x4 f1 = *(const f32x4*)&xt[mrow][kt * 32 + kg + 16];
        H8 hh, ll;
#pragma unroll
        for (int e = 0; e < 4; ++e) {
            _Float16 h0 = (_Float16)f0[e];
            ((_Float16*)&hh)[e] = h0;
            ((_Float16*)&ll)[e] = (_Float16)(f0[e] - (float)h0);
            _Float16 h1 = (_Float16)f1[e];
            ((_Float16*)&hh)[e + 4] = h1;
            ((_Float16*)&ll)[e + 4] = (_Float16)(f1[e] - (float)h1);
        }
        ah[kt] = hh.h;
        al[kt] = ll.h;
    }

    f32x4 acc[16];
#pragma unroll
    for (int nt = 0; nt < 16; ++nt) acc[nt] = (f32x4)0.f;

#pragma unroll
    for (int nt = 0; nt < 16; ++nt) {
        size_t nrow = (size_t)(Nb * 256 + nt * 16 + (l & 15));
#pragma unroll
        for (int kt = 0; kt < 4; ++kt) {
            size_t base = nrow * 128 + kt * 32 + kg;
            half8 bh = load_w_frag(WxThi, base);
            half8 bl = load_w_frag(WxTlo, base);
            acc[nt] = MFMA16(ah[kt], bh, acc[nt]);
            acc[nt] = MFMA16(al[kt], bh, acc[nt]);
            acc[nt] = MFMA16(ah[kt], bl, acc[nt]);
        }
    }

#pragma unroll
    for (int nt = 0; nt < 16; ++nt) {
#pragma unroll
        for (int r = 0; r < 4; ++r) {
            size_t bt = (size_t)Mb * 64 + wave * 16 + 4 * (l >> 4) + r;
            out[bt * 512 + Nb * 256 + nt * 16 + (l & 15)] = acc[nt][r];
        }
    }
}

// ---------------------------------------------------------------------------
// k_seq: R3 sync protocol verbatim. 48 WGs x 512 thr. ranks 0..7: h-rows
// (K=768, NKT=3/wave), ranks 8..11: m-rows (K=256, NKT=1/wave).
// Flags: flags[g*64 + rank*4 + w] = last step finished by finish-wave w.
// ---------------------------------------------------------------------------
#define STATE_U32 (64 * 768)

template <int NKT>
__device__ __forceinline__ void seq_body(int g, int rank, int rowBase, int kbase,
                                         int wave, int l,
                                         const _Float16* __restrict__ Whi,
                                         const _Float16* __restrict__ Wlo,
                                         const float* __restrict__ wmb,
                                         const float* __restrict__ uarr,
                                         const float* __restrict__ Bv,
                                         unsigned int* sbuf, int* flags,
                                         float* out, f32x4 (*pscr)[4][64]) {
    constexpr bool isH = (NKT == 3);
    int kg4 = (l >> 4);
    int kg = kg4 * 4;

    // ---- weight fragments: asm loads -> non-rematerializable -> resident ----
    F4 Bh[4][NKT], Bl[4][NKT];
#pragma unroll
    for (int nt = 0; nt < 4; ++nt) {
#pragma unroll
        for (int kt = 0; kt < NKT; ++kt) {
            int row = rowBase + nt * 16 + (l & 15);
            int cb = kbase / 32 + kt;
            size_t fo = (((size_t)row * 24 + cb) * 4 + kg4) << 3;
            const _Float16* ph = Whi + fo;
            const _Float16* pl = Wlo + fo;
            asm volatile("global_load_dwordx4 %0, %1, off"
                         : "=&v"(Bh[nt][kt].q) : "v"(ph));
            asm volatile("global_load_dwordx4 %0, %1, off"
                         : "=&v"(Bl[nt][kt].q) : "v"(pl));
        }
    }
    asm volatile("s_waitcnt vmcnt(0)" ::: "memory");

    int frow = rowBase + wave * 16 + (l & 15);
    float coefU = 0.f;
    if (wave < 4) coefU = isH ? wmb[frow] : Bv[frow - 512];

    int bA = g * 16 + (l & 15);
    int* gflags = flags + g * 64;

    for (int t = 1; t <= 1024; ++t) {
        // ---- prefetch finish operands (independent of flags) ----
        float pxw[4], uv[4];
        if (wave < 4) {
#pragma unroll
            for (int r = 0; r < 4; ++r) {
                int bG = g * 16 + 4 * (l >> 4) + r;
                uv[r] = uarr[(size_t)bG * 1024 + (t - 1)];
                if (isH)
                    pxw[r] = out[(((size_t)bG << 10) + (t - 1)) * 512 + frow];
            }
        }

        // ---- single wave polls 48 flags with RELAXED loads ----
        if (wave == 7) {
            for (;;) {
                int a = 0x7fffffff;
                if (l < 48)
                    a = ALOAD(&gflags[l]);
                if (__all(a >= t - 1)) break;
                __builtin_amdgcn_s_sleep(1);
            }
        }
        __syncthreads();  // releases all waves once step t-1 fully published

        // ---- state loads (batched, single wait) ----
        const unsigned int* rb = sbuf + (size_t)((t - 1) & 1) * STATE_U32;
        const unsigned int* p0 = rb + (size_t)bA * 768 + kbase + kg;
        u32x4 qa[NKT], qb[NKT];
        if constexpr (NKT == 3) {
            const unsigned int* p1 = p0 + 32;
            const unsigned int* p2 = p0 + 64;
            asm volatile(
                "global_load_dwordx4 %0, %6, off sc1\n\t"
                "global_load_dwordx4 %1, %6, off offset:64 sc1\n\t"
                "global_load_dwordx4 %2, %7, off sc1\n\t"
                "global_load_dwordx4 %3, %7, off offset:64 sc1\n\t"
                "global_load_dwordx4 %4, %8, off sc1\n\t"
                "global_load_dwordx4 %5, %8, off offset:64 sc1\n\t"
                "s_waitcnt vmcnt(0)"
                : "=&v"(qa[0]), "=&v"(qb[0]), "=&v"(qa[1]), "=&v"(qb[1]),
                  "=&v"(qa[2]), "=&v"(qb[2])
                : "v"(p0), "v"(p1), "v"(p2) : "memory");
        } else {
            asm volatile(
                "global_load_dwordx4 %0, %2, off sc1\n\t"
                "global_load_dwordx4 %1, %2, off offset:64 sc1\n\t"
                "s_waitcnt vmcnt(0)"
                : "=&v"(qa[0]), "=&v"(qb[0]) : "v"(p0) : "memory");
        }

        f32x4 acc[4];
#pragma unroll
        for (int nt = 0; nt < 4; ++nt) acc[nt] = (f32x4)0.f;

#pragma unroll
        for (int kt = 0; kt < NKT; ++kt) {
            half8 Ah, Al;
            unpack8(qa[kt], qb[kt], Ah, Al);
#pragma unroll
            for (int nt = 0; nt < 4; ++nt) {
                acc[nt] = MFMA16(Ah, Bh[nt][kt].h, acc[nt]);
                acc[nt] = MFMA16(Al, Bh[nt][kt].h, acc[nt]);
                acc[nt] = MFMA16(Ah, Bl[nt][kt].h, acc[nt]);
            }
        }

        // ---- partial sums to LDS ----
#pragma unroll
        for (int nt = 0; nt < 4; ++nt) pscr[wave][nt][l] = acc[nt];
        __syncthreads();

        // ---- reduce + finish (waves 0..3, wave == nt) ----
        if (wave < 4) {
            f32x4 s = pscr[0][wave][l];
#pragma unroll
            for (int w = 1; w < 8; ++w) s += pscr[w][wave][l];

            unsigned int* wb = sbuf + (size_t)(t & 1) * STATE_U32;
            float vout[4];
#pragma unroll
            for (int r = 0; r < 4; ++r) {
                int bG = g * 16 + 4 * (l >> 4) + r;
                float v = s[r] + coefU * uv[r];
                if (isH) {
                    v += pxw[r];
                    v = (v >= 0.f) ? v : 0.2f * v;
                }
                vout[r] = v;
                _Float16 hi = (_Float16)v;
                _Float16 lo = (_Float16)(v - (float)hi);
                unsigned int pr = (unsigned int)__builtin_bit_cast(unsigned short, hi) |
                                  ((unsigned int)__builtin_bit_cast(unsigned short, lo) << 16);
                ASTORE(wb + (size_t)bG * 768 + frow, pr);
            }
            // Manual release: drain own state stores, then RELAXED flag store.
            asm volatile("s_waitcnt vmcnt(0)" ::: "memory");
            ASTORE(&gflags[rank * 4 + wave], t);
            // Output stores AFTER the flag -- off the critical sync path.
            if (isH) {
#pragma unroll
                for (int r = 0; r < 4; ++r) {
                    int bG = g * 16 + 4 * (l >> 4) + r;
                    out[(((size_t)bG << 10) + (t - 1)) * 512 + frow] = vout[r];
                }
            }
        }
        // No end-of-step barrier needed (see R3 reasoning).
    }
}

__global__ __launch_bounds__(512, 1) void k_seq(const _Float16* __restrict__ Whi,
                                                const _Float16* __restrict__ Wlo,
                                                const float* __restrict__ wmb,
                                                const float* __restrict__ uarr,
                                                const float* __restrict__ Bv,
                                                unsigned int* sbuf, int* flags,
                                                float* out) {
    __shared__ f32x4 pscr[8][4][64];
    int tid = threadIdx.x;
    int wave = tid >> 6, l = tid & 63;
    int g = blockIdx.x / 12, rank = blockIdx.x % 12;
    if (rank < 8) {
        seq_body<3>(g, rank, rank * 64, wave * 96, wave, l, Whi, Wlo, wmb, uarr, Bv,
                    sbuf, flags, out, pscr);
    } else {
        seq_body<1>(g, rank, 512 + (rank - 8) * 64, 512 + wave * 32, wave, l, Whi, Wlo,
                    wmb, uarr, Bv, sbuf, flags, out, pscr);
    }
}

// ---------------------------------------------------------------------------
extern "C" void kernel_launch(void* const* d_in, const int* in_sizes, int n_in,
                              void* d_out, int out_size, void* d_ws, size_t ws_size,
                              hipStream_t stream) {
    const float* x   = (const float*)d_in[0];
    const float* A   = (const float*)d_in[1];
    const float* Bv  = (const float*)d_in[2];
    const float* W_x = (const float*)d_in[3];
    const float* e_x = (const float*)d_in[4];
    const float* W_h = (const float*)d_in[5];
    const float* W_m = (const float*)d_in[6];
    float* out = (float*)d_out;

    char* ws = (char*)d_ws;
    size_t off = 0;
    auto carve = [&](size_t n) -> char* {
        char* p = ws + off;
        off += (n + 255) & ~(size_t)255;
        return p;
    };
    _Float16* Whi   = (_Float16*)carve(768 * 768 * 2);
    _Float16* Wlo   = (_Float16*)carve(768 * 768 * 2);
    _Float16* WxThi = (_Float16*)carve(512 * 128 * 2);
    _Float16* WxTlo = (_Float16*)carve(512 * 128 * 2);
    float* wmb      = (float*)carve(512 * 4);
    float* u        = (float*)carve(64 * 1024 * 4);
    unsigned int* sbuf = (unsigned int*)carve(2 * STATE_U32 * 4);
    int* flags      = (int*)carve(4 * 64 * 4);  // 4 groups x 64 ints

    // zero state ping-pong buffers + flags (adjacent carves)
    hipMemsetAsync(sbuf, 0, (size_t)2 * STATE_U32 * 4 + 4 * 64 * 4, stream);

    hipLaunchKernelGGL(k_prep, dim3(1281), dim3(256), 0, stream, A, Bv, W_x, W_h, W_m,
                       Whi, Wlo, WxThi, WxTlo, wmb);
    hipLaunchKernelGGL(k_u, dim3(256, 64), dim3(256), 0, stream, x, e_x, u);
    hipLaunchKernelGGL(k_pre, dim3(1024, 2), dim3(256), 0, stream, x, WxThi, WxTlo, out);

    void* args[] = {(void*)&Whi, (void*)&Wlo, (void*)&wmb, (void*)&u,
                    (void*)&Bv,  (void*)&sbuf, (void*)&flags, (void*)&out};
    hipLaunchCooperativeKernel((void*)k_seq, dim3(48), dim3(512), args, 0, stream);
}